// Round 3
// baseline (391.185 us; speedup 1.0000x reference)
//
#include <hip/hip_runtime.h>
#include <hip/hip_bf16.h>
#include <math.h>

// B=8, S=2048, D=512, U=512. fp32 in, fp32 out.
// d_out = context [8,2048,512] ++ attn [8,2048,2048]
// Round 3: fused softmax+PV. scores GEMM emits per-tile row max/sumexp stats
// (batch-fastest grid -> XCD-local L2); combine kernel folds stats; pv_fused
// normalizes scores in place (writing final attn) while doing the PV matmul.

typedef __attribute__((ext_vector_type(8))) short short8;
typedef __attribute__((ext_vector_type(4))) float fp32x4;

#define S_DIM 2048
#define D_DIM 512
#define U_DIM 512
#define BATCH 8

#define GLOBAL_AS __attribute__((address_space(1)))
#define LDS_AS __attribute__((address_space(3)))

// RNE float->bf16 (finite inputs only)
__device__ __forceinline__ unsigned short f2bf(float f) {
    unsigned int u = __builtin_bit_cast(unsigned int, f);
    u += 0x7fffu + ((u >> 16) & 1u);
    return (unsigned short)(u >> 16);
}
__device__ __forceinline__ unsigned int pack2bf(float lo, float hi) {
    return ((unsigned int)f2bf(hi) << 16) | f2bf(lo);
}

// async global->LDS, 16 B per lane; LDS dest = wave-uniform base + lane*16
__device__ __forceinline__ void async_copy16(const unsigned short* g, unsigned short* l) {
    __builtin_amdgcn_global_load_lds((const GLOBAL_AS unsigned int*)(const void*)g,
                                     (LDS_AS unsigned int*)(void*)l, 16, 0, 0);
}

__device__ __forceinline__ void storeC(float* p, float v) { *p = v; }
__device__ __forceinline__ void storeC(unsigned short* p, float v) { *p = f2bf(v); }

// ---- generic async NT GEMM (m97-style): C = scale * A @ B^T, bf16 in ----
template <typename CT>
__global__ __launch_bounds__(256) void gemm_nt_async(
    const unsigned short* __restrict__ A, const unsigned short* __restrict__ B,
    CT* __restrict__ C, int lda, int ldb, int ldc, int K,
    long aBatch, long bBatch, long cBatch, float scale) {
    const int tid = threadIdx.x;
    A += (long)blockIdx.z * aBatch;
    B += (long)blockIdx.z * bBatch;
    C += (long)blockIdx.z * cBatch;
    const int m0 = blockIdx.y * 128;
    const int n0 = blockIdx.x * 128;

    __shared__ unsigned short lsA[128 * 32];
    __shared__ unsigned short lsB[128 * 32];

    const int wave = tid >> 6, lane = tid & 63;
    const int wm = (wave & 1) * 64;
    const int wn = (wave >> 1) * 64;
    const int lm = lane & 15;
    const int quad = lane >> 4;

    const int srow = wave * 32 + (lane >> 2);
    const int scol = (lane & 3) * 8;
    const unsigned short* aPtr = A + (long)(m0 + srow) * lda + scol;
    const unsigned short* bPtr = B + (long)(n0 + srow) * ldb + scol;
    unsigned short* aDst0 = &lsA[wave * 1024];
    unsigned short* aDst1 = &lsA[wave * 1024 + 512];
    unsigned short* bDst0 = &lsB[wave * 1024];
    unsigned short* bDst1 = &lsB[wave * 1024 + 512];

    fp32x4 acc[4][4];
#pragma unroll
    for (int i = 0; i < 4; i++)
#pragma unroll
        for (int j = 0; j < 4; j++) acc[i][j] = {0.f, 0.f, 0.f, 0.f};

    for (int k0 = 0; k0 < K; k0 += 32) {
        __syncthreads();
        async_copy16(aPtr, aDst0);
        async_copy16(aPtr + 16 * (long)lda, aDst1);
        async_copy16(bPtr, bDst0);
        async_copy16(bPtr + 16 * (long)ldb, bDst1);
        aPtr += 32;
        bPtr += 32;
        __syncthreads();

        short8 af[4], bf[4];
#pragma unroll
        for (int i = 0; i < 4; i++)
            af[i] = *(const short8*)&lsA[(wm + i * 16 + lm) * 32 + quad * 8];
#pragma unroll
        for (int j = 0; j < 4; j++)
            bf[j] = *(const short8*)&lsB[(wn + j * 16 + lm) * 32 + quad * 8];
#pragma unroll
        for (int i = 0; i < 4; i++)
#pragma unroll
            for (int j = 0; j < 4; j++)
                acc[i][j] = __builtin_amdgcn_mfma_f32_16x16x32_bf16(af[i], bf[j], acc[i][j], 0, 0, 0);
    }

#pragma unroll
    for (int i = 0; i < 4; i++)
#pragma unroll
        for (int j = 0; j < 4; j++) {
            const int m = m0 + wm + i * 16 + quad * 4;
            const int n = n0 + wn + j * 16 + lm;
#pragma unroll
            for (int r = 0; r < 4; r++)
                storeC(&C[(long)(m + r) * ldc + n], acc[i][j][r] * scale);
        }
}

// ---- scores GEMM + per-tile softmax stats. grid (batch=8, mtile=16, ntile=16)
// batch on x => XCD = batch => Q,K of one batch stay in that XCD's L2.
__global__ __launch_bounds__(256) void gemm_scores_stats(
    const unsigned short* __restrict__ Qm, const unsigned short* __restrict__ Km,
    float* __restrict__ Sc, float* __restrict__ Mt, float* __restrict__ Lt,
    float scale) {
    const int tid = threadIdx.x;
    const int b = blockIdx.x;
    const int m0 = blockIdx.y * 128;
    const int n0 = blockIdx.z * 128;
    const int nt = blockIdx.z;
    const unsigned short* A = Qm + (long)b * S_DIM * U_DIM;
    const unsigned short* B = Km + (long)b * S_DIM * U_DIM;
    float* C = Sc + (long)b * S_DIM * S_DIM;

    __shared__ unsigned short lsA[128 * 32];
    __shared__ unsigned short lsB[128 * 32];
    __shared__ float smax[2][128], ssum[2][128];

    const int wave = tid >> 6, lane = tid & 63;
    const int wm = (wave & 1) * 64;
    const int wn = (wave >> 1) * 64;
    const int lm = lane & 15;
    const int quad = lane >> 4;

    const int srow = wave * 32 + (lane >> 2);
    const int scol = (lane & 3) * 8;
    const unsigned short* aPtr = A + (long)(m0 + srow) * U_DIM + scol;
    const unsigned short* bPtr = B + (long)(n0 + srow) * U_DIM + scol;
    unsigned short* aDst0 = &lsA[wave * 1024];
    unsigned short* aDst1 = &lsA[wave * 1024 + 512];
    unsigned short* bDst0 = &lsB[wave * 1024];
    unsigned short* bDst1 = &lsB[wave * 1024 + 512];

    fp32x4 acc[4][4];
#pragma unroll
    for (int i = 0; i < 4; i++)
#pragma unroll
        for (int j = 0; j < 4; j++) acc[i][j] = {0.f, 0.f, 0.f, 0.f};

    for (int k0 = 0; k0 < U_DIM; k0 += 32) {
        __syncthreads();
        async_copy16(aPtr, aDst0);
        async_copy16(aPtr + 16 * U_DIM, aDst1);
        async_copy16(bPtr, bDst0);
        async_copy16(bPtr + 16 * U_DIM, bDst1);
        aPtr += 32;
        bPtr += 32;
        __syncthreads();

        short8 af[4], bf[4];
#pragma unroll
        for (int i = 0; i < 4; i++)
            af[i] = *(const short8*)&lsA[(wm + i * 16 + lm) * 32 + quad * 8];
#pragma unroll
        for (int j = 0; j < 4; j++)
            bf[j] = *(const short8*)&lsB[(wn + j * 16 + lm) * 32 + quad * 8];
#pragma unroll
        for (int i = 0; i < 4; i++)
#pragma unroll
            for (int j = 0; j < 4; j++)
                acc[i][j] = __builtin_amdgcn_mfma_f32_16x16x32_bf16(af[i], bf[j], acc[i][j], 0, 0, 0);
    }

    // store scaled scores
#pragma unroll
    for (int i = 0; i < 4; i++)
#pragma unroll
        for (int j = 0; j < 4; j++) {
            const int m = m0 + wm + i * 16 + quad * 4;
            const int n = n0 + wn + j * 16 + lm;
#pragma unroll
            for (int r = 0; r < 4; r++)
                C[(long)(m + r) * S_DIM + n] = acc[i][j][r] * scale;
        }

    // per-row (max, sum-of-exp) over this wave's 64-col half, then merge halves
    const int half = wn >> 6;  // waves {0,1}->cols 0..63, {2,3}->64..127
#pragma unroll
    for (int i = 0; i < 4; i++) {
#pragma unroll
        for (int r = 0; r < 4; r++) {
            float v = -1e30f;
#pragma unroll
            for (int j = 0; j < 4; j++) v = fmaxf(v, acc[i][j][r]);
            float vs = v * scale;
#pragma unroll
            for (int off = 1; off < 16; off <<= 1) vs = fmaxf(vs, __shfl_xor(vs, off));
            float s = 0.f;
#pragma unroll
            for (int j = 0; j < 4; j++) s += __expf(acc[i][j][r] * scale - vs);
#pragma unroll
            for (int off = 1; off < 16; off <<= 1) s += __shfl_xor(s, off);
            if (lm == 0) {
                const int row = wm + i * 16 + quad * 4 + r;
                smax[half][row] = vs;
                ssum[half][row] = s;
            }
        }
    }
    __syncthreads();
    if (tid < 128) {
        const float M0 = smax[0][tid], M1 = smax[1][tid];
        const float Mx = fmaxf(M0, M1);
        const float L = ssum[0][tid] * __expf(M0 - Mx) + ssum[1][tid] * __expf(M1 - Mx);
        const long row = (long)b * S_DIM + m0 + tid;
        Mt[row * 16 + nt] = Mx;
        Lt[row * 16 + nt] = L;
    }
}

// ---- fold 16 per-tile stats into per-row M and 1/L ----
__global__ __launch_bounds__(256) void combine_stats(
    const float* __restrict__ Mt, const float* __restrict__ Lt,
    float* __restrict__ Mrow, float* __restrict__ invL) {
    const long r = blockIdx.x * 256 + threadIdx.x;  // 16384 rows
    float M = -1e30f;
#pragma unroll
    for (int t = 0; t < 16; t++) M = fmaxf(M, Mt[r * 16 + t]);
    float L = 0.f;
#pragma unroll
    for (int t = 0; t < 16; t++) L += Lt[r * 16 + t] * __expf(Mt[r * 16 + t] - M);
    Mrow[r] = M;
    invL[r] = 1.0f / L;
}

// ---- fused normalize + PV. grid (batch=8, qtile=32), 512 thr = 8 waves.
// Block tile 64q x 512u; wave w covers u in [w*64, w*64+64). Scores are read,
// normalized to attn (written back in place, fp32) and fed as bf16 A-operand.
__global__ __launch_bounds__(512) void pv_fused(
    float* __restrict__ Sc, const unsigned short* __restrict__ Vt,
    float* __restrict__ ctx, const float* __restrict__ Mrow,
    const float* __restrict__ invL) {
    const int tid = threadIdx.x;
    const int b = blockIdx.x;          // XCD = batch (x fastest in dispatch)
    const int q0 = blockIdx.y * 64;
    const int wave = tid >> 6, lane = tid & 63;
    const int lm = lane & 15, quad = lane >> 4;

    float* S = Sc + (long)b * S_DIM * S_DIM;
    const unsigned short* V = Vt + (long)b * U_DIM * S_DIM;

    __shared__ unsigned short lsB[512 * 32];  // Vt tile [512u][32k], 32 KB
    __shared__ unsigned short lsA[64 * 32];   // P tile  [64q][32k] bf16, 4 KB
    __shared__ float lsM[64], lsI[64];

    if (tid < 64) {
        lsM[tid] = Mrow[(long)b * S_DIM + q0 + tid];
        lsI[tid] = invL[(long)b * S_DIM + q0 + tid];
    }

    const int arow = tid >> 3, acol = (tid & 7) * 4;
    float* aPtr = S + (long)(q0 + arow) * S_DIM + acol;
    const int brow = wave * 64 + (lane >> 2);  // +16*t per instruction
    const int bcol = (lane & 3) * 8;
    const unsigned short* bPtr = V + (long)brow * S_DIM + bcol;

    fp32x4 acc[4][4];
#pragma unroll
    for (int i = 0; i < 4; i++)
#pragma unroll
        for (int j = 0; j < 4; j++) acc[i][j] = {0.f, 0.f, 0.f, 0.f};

    for (int k0 = 0; k0 < S_DIM; k0 += 32) {
        __syncthreads();  // also covers initial lsM/lsI visibility
        // Vt tile: 4 async instrs/wave, 16 rows each
#pragma unroll
        for (int t = 0; t < 4; t++)
            async_copy16(bPtr + (long)(16 * t) * S_DIM + k0,
                         &lsB[(wave * 64 + 16 * t) * 32]);
        // P tile: read scores, normalize, write attn in place, bf16 -> LDS
        float4 s4 = *(float4*)(aPtr + k0);
        const float m = lsM[arow], il = lsI[arow];
        s4.x = __expf(s4.x - m) * il;
        s4.y = __expf(s4.y - m) * il;
        s4.z = __expf(s4.z - m) * il;
        s4.w = __expf(s4.w - m) * il;
        *(float4*)(aPtr + k0) = s4;
        ((uint2*)lsA)[tid] = make_uint2(pack2bf(s4.x, s4.y), pack2bf(s4.z, s4.w));
        __syncthreads();

        short8 af[4], bf[4];
#pragma unroll
        for (int i = 0; i < 4; i++)
            af[i] = *(const short8*)&lsA[(i * 16 + lm) * 32 + quad * 8];
#pragma unroll
        for (int j = 0; j < 4; j++)
            bf[j] = *(const short8*)&lsB[(wave * 64 + j * 16 + lm) * 32 + quad * 8];
#pragma unroll
        for (int i = 0; i < 4; i++)
#pragma unroll
            for (int j = 0; j < 4; j++)
                acc[i][j] = __builtin_amdgcn_mfma_f32_16x16x32_bf16(af[i], bf[j], acc[i][j], 0, 0, 0);
    }

#pragma unroll
    for (int i = 0; i < 4; i++)
#pragma unroll
        for (int j = 0; j < 4; j++) {
            const int mq = q0 + i * 16 + quad * 4;
            const int u = wave * 64 + j * 16 + lm;
#pragma unroll
            for (int r = 0; r < 4; r++)
                ctx[((long)b * S_DIM + mq + r) * U_DIM + u] = acc[i][j][r];
        }
}

// ---- fallback NT GEMM (sync staging, fp32 A) ----
__device__ __forceinline__ void stage16(unsigned short* dst, const float* src) {
#pragma unroll
    for (int c = 0; c < 16; c += 4) {
        float4 f = *(const float4*)(src + c);
        dst[c + 0] = f2bf(f.x);
        dst[c + 1] = f2bf(f.y);
        dst[c + 2] = f2bf(f.z);
        dst[c + 3] = f2bf(f.w);
    }
}
__global__ __launch_bounds__(256) void gemm_nt_f32a(
    const float* __restrict__ A, const unsigned short* __restrict__ B,
    float* __restrict__ C, int lda, int ldb, int ldc, int K,
    long aBatch, long bBatch, long cBatch, float scale) {
    const int tid = threadIdx.x;
    A += (long)blockIdx.z * aBatch;
    B += (long)blockIdx.z * bBatch;
    C += (long)blockIdx.z * cBatch;
    const int m0 = blockIdx.y * 128;
    const int n0 = blockIdx.x * 128;

    __shared__ unsigned short lsA[128 * 40];
    __shared__ unsigned short lsB[128 * 40];

    const int wave = tid >> 6, lane = tid & 63;
    const int wm = (wave & 1) * 64;
    const int wn = (wave >> 1) * 64;
    const int lm = lane & 15;
    const int quad = lane >> 4;
    const int sr = tid >> 1;
    const int sc = (tid & 1) * 16;

    fp32x4 acc[4][4];
#pragma unroll
    for (int i = 0; i < 4; i++)
#pragma unroll
        for (int j = 0; j < 4; j++) acc[i][j] = {0.f, 0.f, 0.f, 0.f};

    for (int k0 = 0; k0 < K; k0 += 32) {
        __syncthreads();
        stage16(&lsA[sr * 40 + sc], A + (long)(m0 + sr) * lda + k0 + sc);
        {
            const unsigned short* s = B + (long)(n0 + sr) * ldb + k0 + sc;
            *(short8*)&lsB[sr * 40 + sc] = *(const short8*)s;
            *(short8*)&lsB[sr * 40 + sc + 8] = *(const short8*)(s + 8);
        }
        __syncthreads();

        short8 af[4], bf[4];
#pragma unroll
        for (int i = 0; i < 4; i++)
            af[i] = *(const short8*)&lsA[(wm + i * 16 + lm) * 40 + quad * 8];
#pragma unroll
        for (int j = 0; j < 4; j++)
            bf[j] = *(const short8*)&lsB[(wn + j * 16 + lm) * 40 + quad * 8];
#pragma unroll
        for (int i = 0; i < 4; i++)
#pragma unroll
            for (int j = 0; j < 4; j++)
                acc[i][j] = __builtin_amdgcn_mfma_f32_16x16x32_bf16(af[i], bf[j], acc[i][j], 0, 0, 0);
    }
#pragma unroll
    for (int i = 0; i < 4; i++)
#pragma unroll
        for (int j = 0; j < 4; j++) {
            const int m = m0 + wm + i * 16 + quad * 4;
            const int n = n0 + wn + j * 16 + lm;
#pragma unroll
            for (int r = 0; r < 4; r++)
                C[(long)(m + r) * ldc + n] = acc[i][j][r] * scale;
        }
}

// ---- X fp32 -> bf16 ----
__global__ __launch_bounds__(256) void convert_x(const float* __restrict__ X,
                                                 unsigned short* __restrict__ Xb) {
    const int i = blockIdx.x * 256 + threadIdx.x;
    float4 f = ((const float4*)X)[i];
    ((uint2*)Xb)[i] = make_uint2(pack2bf(f.x, f.y), pack2bf(f.z, f.w));
}

// ---- W [D,U] fp32 -> Wt [U,D] bf16 ----
__global__ __launch_bounds__(256) void transpose_w(const float* __restrict__ W,
                                                   unsigned short* __restrict__ Wt) {
    __shared__ float t[32][33];
    const int tx = threadIdx.x & 31, ty = threadIdx.x >> 5;
    const int d0 = blockIdx.y * 32, u0 = blockIdx.x * 32;
#pragma unroll
    for (int i = 0; i < 32; i += 8) t[ty + i][tx] = W[(long)(d0 + ty + i) * U_DIM + u0 + tx];
    __syncthreads();
#pragma unroll
    for (int i = 0; i < 32; i += 8)
        Wt[(long)(u0 + ty + i) * D_DIM + d0 + tx] = f2bf(t[tx][ty + i]);
}

// ---- V [S,U] bf16 -> Vt [U,S] bf16, per batch ----
__global__ __launch_bounds__(256) void transpose_v(const unsigned short* __restrict__ V,
                                                   unsigned short* __restrict__ Vt) {
    V += (long)blockIdx.z * S_DIM * U_DIM;
    Vt += (long)blockIdx.z * U_DIM * S_DIM;
    __shared__ unsigned short t[32][33];
    const int tx = threadIdx.x & 31, ty = threadIdx.x >> 5;
    const int s0 = blockIdx.y * 32, u0 = blockIdx.x * 32;
#pragma unroll
    for (int i = 0; i < 32; i += 8) t[ty + i][tx] = V[(long)(s0 + ty + i) * U_DIM + u0 + tx];
    __syncthreads();
#pragma unroll
    for (int i = 0; i < 32; i += 8)
        Vt[(long)(u0 + ty + i) * S_DIM + s0 + tx] = t[tx][ty + i];
}

// ---- fallback row softmax in place ----
__global__ __launch_bounds__(256) void softmax_rows(float* __restrict__ attn) {
    float4* p = (float4*)(attn + (long)blockIdx.x * S_DIM);
    const int tid = threadIdx.x;
    const int lane = tid & 63, wave = tid >> 6;
    float4 a = p[tid];
    float4 b = p[tid + 256];

    float mx = fmaxf(fmaxf(fmaxf(a.x, a.y), fmaxf(a.z, a.w)),
                     fmaxf(fmaxf(b.x, b.y), fmaxf(b.z, b.w)));
#pragma unroll
    for (int off = 32; off > 0; off >>= 1) mx = fmaxf(mx, __shfl_down(mx, off));
    __shared__ float red[8];
    if (lane == 0) red[wave] = mx;
    __syncthreads();
    const float rowmax = fmaxf(fmaxf(red[0], red[1]), fmaxf(red[2], red[3]));

    a.x = __expf(a.x - rowmax); a.y = __expf(a.y - rowmax);
    a.z = __expf(a.z - rowmax); a.w = __expf(a.w - rowmax);
    b.x = __expf(b.x - rowmax); b.y = __expf(b.y - rowmax);
    b.z = __expf(b.z - rowmax); b.w = __expf(b.w - rowmax);
    float s = a.x + a.y + a.z + a.w + b.x + b.y + b.z + b.w;
#pragma unroll
    for (int off = 32; off > 0; off >>= 1) s += __shfl_down(s, off);
    if (lane == 0) red[4 + wave] = s;
    __syncthreads();
    const float inv = 1.0f / (red[4] + red[5] + red[6] + red[7]);

    a.x *= inv; a.y *= inv; a.z *= inv; a.w *= inv;
    b.x *= inv; b.y *= inv; b.z *= inv; b.w *= inv;
    p[tid] = a;
    p[tid + 256] = b;
}

extern "C" void kernel_launch(void* const* d_in, const int* in_sizes, int n_in,
                              void* d_out, int out_size, void* d_ws, size_t ws_size,
                              hipStream_t stream) {
    const float* X  = (const float*)d_in[0];
    const float* Wq = (const float*)d_in[1];
    const float* Wk = (const float*)d_in[2];
    const float* Wv = (const float*)d_in[3];

    float* ctx  = (float*)d_out;
    float* attn = (float*)d_out + (size_t)BATCH * S_DIM * U_DIM;

    const size_t MTOT = (size_t)BATCH * S_DIM;  // 16384
    // ws (ushort elems): Xb | Wt | QKV | stats. Vt aliases Xb.
    unsigned short* Xb  = (unsigned short*)d_ws;           // 16.8 MB
    unsigned short* Wt  = Xb + MTOT * D_DIM;               // 1.6 MB
    unsigned short* QKV = Wt + (size_t)3 * U_DIM * D_DIM;  // 50.3 MB
    unsigned short* Vt  = Xb;
    float* Mt   = (float*)(QKV + (size_t)3 * MTOT * U_DIM);  // 1 MB
    float* Lt   = Mt + MTOT * 16;                            // 1 MB
    float* Mrow = Lt + MTOT * 16;                            // 64 KB
    float* invL = Mrow + MTOT;                               // 64 KB

    unsigned short* Q  = QKV;
    unsigned short* Km = QKV + MTOT * U_DIM;
    unsigned short* V  = QKV + 2 * MTOT * U_DIM;

    const size_t need = (size_t)((char*)(invL + MTOT) - (char*)d_ws);
    const bool fast = ws_size >= need;

    convert_x<<<dim3((unsigned)(MTOT * D_DIM / 4 / 256)), 256, 0, stream>>>(X, Xb);
    transpose_w<<<dim3(16, 16), 256, 0, stream>>>(Wq, Wt);
    transpose_w<<<dim3(16, 16), 256, 0, stream>>>(Wk, Wt + (size_t)U_DIM * D_DIM);
    transpose_w<<<dim3(16, 16), 256, 0, stream>>>(Wv, Wt + (size_t)2 * U_DIM * D_DIM);

    // QKV = X @ W: M=16384, N=512, K=512 (z over {q,k,v})
    gemm_nt_async<unsigned short><<<dim3(4, 128, 3), 256, 0, stream>>>(
        Xb, Wt, QKV, D_DIM, D_DIM, U_DIM, D_DIM,
        0L, (long)U_DIM * D_DIM, (long)MTOT * U_DIM, 1.0f);

    transpose_v<<<dim3(16, 64, BATCH), 256, 0, stream>>>(V, Vt);

    const float scale = 1.0f / sqrtf((float)U_DIM);
    if (fast) {
        // scores (+stats), batch-fastest grid for XCD-local L2
        gemm_scores_stats<<<dim3(BATCH, 16, 16), 256, 0, stream>>>(
            Q, Km, attn, Mt, Lt, scale);
        combine_stats<<<dim3((unsigned)(MTOT / 256)), 256, 0, stream>>>(Mt, Lt, Mrow, invL);
        // fused normalize + attn-write + PV
        pv_fused<<<dim3(BATCH, 32), 512, 0, stream>>>(attn, Vt, ctx, Mrow, invL);
    } else {
        gemm_nt_async<float><<<dim3(16, 16, BATCH), 256, 0, stream>>>(
            Q, Km, attn, U_DIM, U_DIM, S_DIM, U_DIM,
            (long)S_DIM * U_DIM, (long)S_DIM * U_DIM, (long)S_DIM * S_DIM, scale);
        softmax_rows<<<dim3((unsigned)MTOT), 256, 0, stream>>>(attn);
        gemm_nt_f32a<<<dim3(4, 16, BATCH), 256, 0, stream>>>(
            attn, Vt, ctx, S_DIM, S_DIM, U_DIM, S_DIM,
            (long)S_DIM * S_DIM, (long)U_DIM * S_DIM, (long)S_DIM * U_DIM, 1.0f);
    }
}